// Round 10
// baseline (320.569 us; speedup 1.0000x reference)
//
#include <hip/hip_runtime.h>
#include <hip/hip_bf16.h>

// TupleAveragePredictor: out = sigmoid( relu( [mean(gnn_h[tuples[:,1:]]), gnn_h[triplets[:,2]]] @ W1^T + b1 ) @ W2^T + b2 )
// R10: occupancy test. BM=32 (acc[2][4]=32 AGPR, LDS 35.3 KB) with
// __launch_bounds__(512,6) -> 24 waves/CU (was 16). Gather math byte-identical
// to R6/R9 (absmax invariant 0.00390625). W1 L2-stream doubles (cheap; L2 has
// 5x headroom). Discriminates wave-concurrency-bound vs per-CU-fabric-bound.

#define NROWS 200000
#define NNODES 100000
#define INF 256
#define KDIM 512
#define HF 512
#define BM 32

typedef __attribute__((ext_vector_type(8))) short short8;
typedef __attribute__((ext_vector_type(4))) float f32x4;
typedef __attribute__((ext_vector_type(2))) float f32x2;

__device__ __align__(16) unsigned short g_hb[NNODES * INF];   // 51.2 MB bf16 (target reads)
__device__ __align__(16) unsigned char  g_h8[NNODES * INF];   // 25.6 MB fp8 e4m3 (avg reads)
__device__ __align__(16) unsigned short g_W1p[HF * KDIM];     // 512 KB fragment-packed W1

__device__ __forceinline__ unsigned short f2bf(float f) {
    unsigned int u = __float_as_uint(f);
    return (unsigned short)((u + 0x7fffu + ((u >> 16) & 1u)) >> 16);
}
__device__ __forceinline__ unsigned long long pk4(float a, float b, float c, float d) {
    return (unsigned long long)f2bf(a) | ((unsigned long long)f2bf(b) << 16)
         | ((unsigned long long)f2bf(c) << 32) | ((unsigned long long)f2bf(d) << 48);
}

// gnn_h fp32 -> bf16 table AND fp8 table, 8 elems/thread (12500 blocks x 256).
__global__ void convert_h_kernel(const float* __restrict__ gnn_h) {
    int i = (blockIdx.x * 256 + threadIdx.x) * 8;
    float4 a = *(const float4*)(gnn_h + i);
    float4 b = *(const float4*)(gnn_h + i + 4);
    ulonglong2 v;
    v.x = pk4(a.x, a.y, a.z, a.w);
    v.y = pk4(b.x, b.y, b.z, b.w);
    *(ulonglong2*)(g_hb + i) = v;
    int w0 = __builtin_amdgcn_cvt_pk_fp8_f32(a.x, a.y, 0, 0);
    w0     = __builtin_amdgcn_cvt_pk_fp8_f32(a.z, a.w, w0, 1);
    int w1 = __builtin_amdgcn_cvt_pk_fp8_f32(b.x, b.y, 0, 0);
    w1     = __builtin_amdgcn_cvt_pk_fp8_f32(b.z, b.w, w1, 1);
    *(uint2*)(g_h8 + i) = make_uint2((unsigned)w0, (unsigned)w1);
}

// W1 -> bf16 packed in B-fragment order (unchanged):
// packed[(c*16+ki)*512 + lane*8 + j] = W1[col=c*16+(lane&15)][k=ki*32+(lane>>4)*8+j]
__global__ void pack_w1_kernel(const float* __restrict__ W1) {
    int p = (blockIdx.x * 256 + threadIdx.x) * 4;  // 262144/4 = 65536 thr
    int chunk  = p >> 9;
    int within = p & 511;
    int lane = within >> 3;
    int j0   = within & 7;
    int c  = chunk >> 4, ki = chunk & 15;
    int col = c * 16 + (lane & 15);
    int k   = ki * 32 + (lane >> 4) * 8 + j0;
    float4 v = *(const float4*)(W1 + col * KDIM + k);
    *(unsigned long long*)(g_W1p + p) = pk4(v.x, v.y, v.z, v.w);
}

__global__ __launch_bounds__(512, 6)
void fused_kernel(const int* __restrict__ tuples,
                  const int* __restrict__ triplets,
                  const float* __restrict__ b1,
                  const float* __restrict__ W2,
                  const float* __restrict__ b2,
                  float* __restrict__ out) {
    __shared__ __align__(16) unsigned short x_lds[BM * KDIM];  // 32 KB, swizzled
    __shared__ int idx_lds[BM * 11];
    __shared__ int tgt_lds[BM];
    __shared__ float red[8][BM];

    const int t = threadIdx.x;
    const int g0 = blockIdx.x * BM;
    const int lane = t & 63;
    const int wc = t >> 6;

    // ---- stage indices ----
    for (int i = t; i < BM * 11; i += 512) idx_lds[i] = tuples[g0 * 11 + i];
    if (t < BM) tgt_lds[t] = triplets[(g0 + t) * 3 + 2];
    __syncthreads();

    // ---- gather: 16 rows/step (32 lanes per row), 2 steps (= R6 body) ----
    // avg half from fp8 table (8B/lane), tgt half from bf16 table (16B/lane).
    // swizzled LDS: phys = L ^ ((row&7)<<4), L = row*1024 + half*512 + l32*16
    const int rgrp = t >> 5;
    const int l32 = t & 31;
    for (int step = 0; step < BM / 16; ++step) {
        const int r = step * 16 + rgrp;
        uint2 u[10];
        #pragma unroll
        for (int i = 0; i < 10; ++i) {
            int node = idx_lds[r * 11 + 1 + i];
            node = min(max(node, 0), NNODES - 1);
            u[i] = *(const uint2*)(g_h8 + node * INF + l32 * 8);
        }
        int tg = tgt_lds[r];
        tg = min(max(tg, 0), NNODES - 1);
        const short8 ut = *(const short8*)(g_hb + tg * INF + l32 * 8);

        f32x2 s0 = {0.f, 0.f}, s1 = {0.f, 0.f}, s2 = {0.f, 0.f}, s3 = {0.f, 0.f};
        #pragma unroll
        for (int i = 0; i < 10; ++i) {
            s0 += __builtin_amdgcn_cvt_pk_f32_fp8((int)u[i].x, 0);
            s1 += __builtin_amdgcn_cvt_pk_f32_fp8((int)u[i].x, 1);
            s2 += __builtin_amdgcn_cvt_pk_f32_fp8((int)u[i].y, 0);
            s3 += __builtin_amdgcn_cvt_pk_f32_fp8((int)u[i].y, 1);
        }

        ulonglong2 avg;
        avg.x = pk4(s0.x * 0.1f, s0.y * 0.1f, s1.x * 0.1f, s1.y * 0.1f);
        avg.y = pk4(s2.x * 0.1f, s2.y * 0.1f, s3.x * 0.1f, s3.y * 0.1f);
        const int x = (r & 7) << 4;
        *(ulonglong2*)((char*)x_lds + ((r * 1024 + l32 * 16) ^ x)) = avg;
        *(short8*)((char*)x_lds + ((r * 1024 + 512 + l32 * 16) ^ x)) = ut;
    }
    __syncthreads();

    // ---- MFMA: wave wc owns h-cols [wc*64, wc*64+64), acc[2][4] ----
    const int arow = lane & 15;
    const int kgrp = lane >> 4;

    f32x4 acc[2][4];
    #pragma unroll
    for (int rt = 0; rt < 2; ++rt)
        #pragma unroll
        for (int ct = 0; ct < 4; ++ct)
            acc[rt][ct] = (f32x4){0.f, 0.f, 0.f, 0.f};

    const int xsw = (arow & 7) << 4;
    for (int ki = 0; ki < 16; ++ki) {
        short8 a[2];
        #pragma unroll
        for (int rt = 0; rt < 2; ++rt) {
            const int loff = (rt * 16 + arow) * 1024 + ki * 64 + kgrp * 16;
            a[rt] = *(const short8*)((const char*)x_lds + (loff ^ xsw));
        }
        #pragma unroll
        for (int ct = 0; ct < 4; ++ct) {
            const short8 b = *(const short8*)(g_W1p + ((wc * 4 + ct) * 16 + ki) * 512 + lane * 8);
            #pragma unroll
            for (int rt = 0; rt < 2; ++rt)
                acc[rt][ct] = __builtin_amdgcn_mfma_f32_16x16x32_bf16(a[rt], b, acc[rt][ct], 0, 0, 0);
        }
    }

    // ---- epilogue: relu + dot(W2) + reduce + sigmoid ----
    // b1/W2 loaded here (post-MFMA) to keep gather-phase registers lean.
    float b1r[4], w2r[4];
    #pragma unroll
    for (int ct = 0; ct < 4; ++ct) {
        b1r[ct] = b1[wc * 64 + ct * 16 + arow];
        w2r[ct] = W2[wc * 64 + ct * 16 + arow];
    }

    // D mapping: col = wc*64 + ct*16 + (lane&15), row = rt*16 + kgrp*4 + reg
    #pragma unroll
    for (int rt = 0; rt < 2; ++rt) {
        #pragma unroll
        for (int reg = 0; reg < 4; ++reg) {
            float s = 0.f;
            #pragma unroll
            for (int ct = 0; ct < 4; ++ct) {
                float h = acc[rt][ct][reg] + b1r[ct];
                s += fmaxf(h, 0.f) * w2r[ct];
            }
            s += __shfl_xor(s, 1, 64);
            s += __shfl_xor(s, 2, 64);
            s += __shfl_xor(s, 4, 64);
            s += __shfl_xor(s, 8, 64);
            if ((lane & 15) == 0)
                red[wc][rt * 16 + kgrp * 4 + reg] = s;
        }
    }
    __syncthreads();

    if (t < BM) {
        float s = b2[0];
        #pragma unroll
        for (int i = 0; i < 8; ++i) s += red[i][t];
        out[g0 + t] = 1.f / (1.f + expf(-s));
    }
}

extern "C" void kernel_launch(void* const* d_in, const int* in_sizes, int n_in,
                              void* d_out, int out_size, void* d_ws, size_t ws_size,
                              hipStream_t stream) {
    const float* gnn_h    = (const float*)d_in[0];
    const int*   tuples   = (const int*)d_in[1];
    const int*   triplets = (const int*)d_in[2];
    const float* W1       = (const float*)d_in[3];
    const float* b1       = (const float*)d_in[4];
    const float* W2       = (const float*)d_in[5];
    const float* b2       = (const float*)d_in[6];
    float* out = (float*)d_out;

    convert_h_kernel<<<dim3(NNODES * INF / (256 * 8)), dim3(256), 0, stream>>>(gnn_h);
    pack_w1_kernel<<<dim3(HF * KDIM / (256 * 4)), dim3(256), 0, stream>>>(W1);
    fused_kernel<<<dim3(NROWS / BM), dim3(512), 0, stream>>>(
        tuples, triplets, b1, W2, b2, out);
}

// Round 11
// 258.086 us; speedup vs baseline: 1.2421x; 1.2421x over previous
//
#include <hip/hip_runtime.h>
#include <hip/hip_bf16.h>

// TupleAveragePredictor: out = sigmoid( relu( [mean(gnn_h[tuples[:,1:]]), gnn_h[triplets[:,2]]] @ W1^T + b1 ) @ W2^T + b2 )
// R11 = R6 (245us anchor, BM=64, 8 waves, fp8 avg gather, packed bf16 W1)
// + nontemporal tgt-row loads: the bf16 tgt table (102 MB/dispatch, 2x reuse)
// thrashes L2 against the 20x-reuse fp8 table and the hot 512 KB W1 stream
// (R10 showed B-stream is exposed: doubling it cost 38us). nt = no L2
// allocate for the low-reuse stream. Values bit-identical to R6.

#define NROWS 200000
#define NNODES 100000
#define INF 256
#define KDIM 512
#define HF 512
#define BM 64

typedef __attribute__((ext_vector_type(8))) short short8;
typedef __attribute__((ext_vector_type(4))) float f32x4;
typedef __attribute__((ext_vector_type(2))) float f32x2;

__device__ __align__(16) unsigned short g_hb[NNODES * INF];   // 51.2 MB bf16 (target reads)
__device__ __align__(16) unsigned char  g_h8[NNODES * INF];   // 25.6 MB fp8 e4m3 (avg reads)
__device__ __align__(16) unsigned short g_W1p[HF * KDIM];     // 512 KB fragment-packed W1

__device__ __forceinline__ unsigned short f2bf(float f) {
    unsigned int u = __float_as_uint(f);
    return (unsigned short)((u + 0x7fffu + ((u >> 16) & 1u)) >> 16);
}
__device__ __forceinline__ unsigned long long pk4(float a, float b, float c, float d) {
    return (unsigned long long)f2bf(a) | ((unsigned long long)f2bf(b) << 16)
         | ((unsigned long long)f2bf(c) << 32) | ((unsigned long long)f2bf(d) << 48);
}

// gnn_h fp32 -> bf16 table AND fp8 table, 8 elems/thread (12500 blocks x 256).
__global__ void convert_h_kernel(const float* __restrict__ gnn_h) {
    int i = (blockIdx.x * 256 + threadIdx.x) * 8;
    float4 a = *(const float4*)(gnn_h + i);
    float4 b = *(const float4*)(gnn_h + i + 4);
    ulonglong2 v;
    v.x = pk4(a.x, a.y, a.z, a.w);
    v.y = pk4(b.x, b.y, b.z, b.w);
    *(ulonglong2*)(g_hb + i) = v;
    int w0 = __builtin_amdgcn_cvt_pk_fp8_f32(a.x, a.y, 0, 0);
    w0     = __builtin_amdgcn_cvt_pk_fp8_f32(a.z, a.w, w0, 1);
    int w1 = __builtin_amdgcn_cvt_pk_fp8_f32(b.x, b.y, 0, 0);
    w1     = __builtin_amdgcn_cvt_pk_fp8_f32(b.z, b.w, w1, 1);
    *(uint2*)(g_h8 + i) = make_uint2((unsigned)w0, (unsigned)w1);
}

// W1 -> bf16 packed in B-fragment order (unchanged):
// packed[(c*16+ki)*512 + lane*8 + j] = W1[col=c*16+(lane&15)][k=ki*32+(lane>>4)*8+j]
__global__ void pack_w1_kernel(const float* __restrict__ W1) {
    int p = (blockIdx.x * 256 + threadIdx.x) * 4;  // 262144/4 = 65536 thr
    int chunk  = p >> 9;
    int within = p & 511;
    int lane = within >> 3;
    int j0   = within & 7;
    int c  = chunk >> 4, ki = chunk & 15;
    int col = c * 16 + (lane & 15);
    int k   = ki * 32 + (lane >> 4) * 8 + j0;
    float4 v = *(const float4*)(W1 + col * KDIM + k);
    *(unsigned long long*)(g_W1p + p) = pk4(v.x, v.y, v.z, v.w);
}

__global__ __launch_bounds__(512, 4)
void fused_kernel(const int* __restrict__ tuples,
                  const int* __restrict__ triplets,
                  const float* __restrict__ b1,
                  const float* __restrict__ W2,
                  const float* __restrict__ b2,
                  float* __restrict__ out) {
    __shared__ __align__(16) unsigned short x_lds[BM * KDIM];  // 64 KB, swizzled
    __shared__ int idx_lds[BM * 11];
    __shared__ int tgt_lds[BM];
    __shared__ float red[8][BM];

    const int t = threadIdx.x;
    const int g0 = blockIdx.x * BM;
    const int lane = t & 63;
    const int wc = t >> 6;

    // ---- stage indices ----
    for (int i = t; i < BM * 11; i += 512) idx_lds[i] = tuples[g0 * 11 + i];
    if (t < BM) tgt_lds[t] = triplets[(g0 + t) * 3 + 2];
    __syncthreads();

    // ---- gather: 16 rows/step (32 lanes per row), 4 steps (= R6 body) ----
    // avg half from fp8 table (8B/lane, cached: 20x reuse), tgt half from
    // bf16 table (16B/lane, NONTEMPORAL: 2x reuse, don't pollute L2).
    // swizzled LDS: phys = L ^ ((row&7)<<4), L = row*1024 + half*512 + l32*16
    const int rgrp = t >> 5;
    const int l32 = t & 31;
    for (int step = 0; step < BM / 16; ++step) {
        const int r = step * 16 + rgrp;
        uint2 u[10];
        #pragma unroll
        for (int i = 0; i < 10; ++i) {
            int node = idx_lds[r * 11 + 1 + i];
            node = min(max(node, 0), NNODES - 1);
            u[i] = *(const uint2*)(g_h8 + node * INF + l32 * 8);
        }
        int tg = tgt_lds[r];
        tg = min(max(tg, 0), NNODES - 1);
        const short8 ut = __builtin_nontemporal_load(
            (const short8*)(g_hb + tg * INF + l32 * 8));

        f32x2 s0 = {0.f, 0.f}, s1 = {0.f, 0.f}, s2 = {0.f, 0.f}, s3 = {0.f, 0.f};
        #pragma unroll
        for (int i = 0; i < 10; ++i) {
            s0 += __builtin_amdgcn_cvt_pk_f32_fp8((int)u[i].x, 0);
            s1 += __builtin_amdgcn_cvt_pk_f32_fp8((int)u[i].x, 1);
            s2 += __builtin_amdgcn_cvt_pk_f32_fp8((int)u[i].y, 0);
            s3 += __builtin_amdgcn_cvt_pk_f32_fp8((int)u[i].y, 1);
        }

        ulonglong2 avg;
        avg.x = pk4(s0.x * 0.1f, s0.y * 0.1f, s1.x * 0.1f, s1.y * 0.1f);
        avg.y = pk4(s2.x * 0.1f, s2.y * 0.1f, s3.x * 0.1f, s3.y * 0.1f);
        const int x = (r & 7) << 4;
        *(ulonglong2*)((char*)x_lds + ((r * 1024 + l32 * 16) ^ x)) = avg;
        *(short8*)((char*)x_lds + ((r * 1024 + 512 + l32 * 16) ^ x)) = ut;
    }
    __syncthreads();

    // ---- MFMA: wave wc owns h-cols [wc*64, wc*64+64), acc[4][4] (= R6) ----
    const int arow = lane & 15;
    const int kgrp = lane >> 4;

    f32x4 acc[4][4];
    #pragma unroll
    for (int rt = 0; rt < 4; ++rt)
        #pragma unroll
        for (int ct = 0; ct < 4; ++ct)
            acc[rt][ct] = (f32x4){0.f, 0.f, 0.f, 0.f};

    const int xsw = (arow & 7) << 4;
    for (int ki = 0; ki < 16; ++ki) {
        short8 a[4];
        #pragma unroll
        for (int rt = 0; rt < 4; ++rt) {
            const int loff = (rt * 16 + arow) * 1024 + ki * 64 + kgrp * 16;
            a[rt] = *(const short8*)((const char*)x_lds + (loff ^ xsw));
        }
        #pragma unroll
        for (int ct = 0; ct < 4; ++ct) {
            const short8 b = *(const short8*)(g_W1p + ((wc * 4 + ct) * 16 + ki) * 512 + lane * 8);
            #pragma unroll
            for (int rt = 0; rt < 4; ++rt)
                acc[rt][ct] = __builtin_amdgcn_mfma_f32_16x16x32_bf16(a[rt], b, acc[rt][ct], 0, 0, 0);
        }
    }

    // ---- epilogue: relu + dot(W2) + reduce + sigmoid ----
    // b1/W2 loaded here (post-MFMA) to keep gather/MFMA registers lean.
    float b1r[4], w2r[4];
    #pragma unroll
    for (int ct = 0; ct < 4; ++ct) {
        b1r[ct] = b1[wc * 64 + ct * 16 + arow];
        w2r[ct] = W2[wc * 64 + ct * 16 + arow];
    }

    // D mapping: col = wc*64 + ct*16 + (lane&15), row = rt*16 + kgrp*4 + reg
    #pragma unroll
    for (int rt = 0; rt < 4; ++rt) {
        #pragma unroll
        for (int reg = 0; reg < 4; ++reg) {
            float s = 0.f;
            #pragma unroll
            for (int ct = 0; ct < 4; ++ct) {
                float h = acc[rt][ct][reg] + b1r[ct];
                s += fmaxf(h, 0.f) * w2r[ct];
            }
            s += __shfl_xor(s, 1, 64);
            s += __shfl_xor(s, 2, 64);
            s += __shfl_xor(s, 4, 64);
            s += __shfl_xor(s, 8, 64);
            if ((lane & 15) == 0)
                red[wc][rt * 16 + kgrp * 4 + reg] = s;
        }
    }
    __syncthreads();

    if (t < BM) {
        float s = b2[0];
        #pragma unroll
        for (int i = 0; i < 8; ++i) s += red[i][t];
        out[g0 + t] = 1.f / (1.f + expf(-s));
    }
}

extern "C" void kernel_launch(void* const* d_in, const int* in_sizes, int n_in,
                              void* d_out, int out_size, void* d_ws, size_t ws_size,
                              hipStream_t stream) {
    const float* gnn_h    = (const float*)d_in[0];
    const int*   tuples   = (const int*)d_in[1];
    const int*   triplets = (const int*)d_in[2];
    const float* W1       = (const float*)d_in[3];
    const float* b1       = (const float*)d_in[4];
    const float* W2       = (const float*)d_in[5];
    const float* b2       = (const float*)d_in[6];
    float* out = (float*)d_out;

    convert_h_kernel<<<dim3(NNODES * INF / (256 * 8)), dim3(256), 0, stream>>>(gnn_h);
    pack_w1_kernel<<<dim3(HF * KDIM / (256 * 4)), dim3(256), 0, stream>>>(W1);
    fused_kernel<<<dim3(NROWS / BM), dim3(512), 0, stream>>>(
        tuples, triplets, b1, W2, b2, out);
}

// Round 12
// 230.318 us; speedup vs baseline: 1.3919x; 1.1206x over previous
//
#include <hip/hip_runtime.h>
#include <hip/hip_bf16.h>

// TupleAveragePredictor: out = sigmoid( relu( [mean(gnn_h[tuples[:,1:]]), gnn_h[triplets[:,2]]] @ W1^T + b1 ) @ W2^T + b2 )
// R12: full-fp8 pipeline. One 25.6 MB fp8 node table serves avg AND tgt
// gathers (tgt row 512->256 B); W1 packed fp8 (256 KB, halves the exposed
// per-block B-stream R10 proved costly); single mfma_fp8_fp8 K-loop (no
// R7 dual-path register pressure). LDS x-tile fp8 32 KB, swizzle
// phys = L ^ ((row&15)<<3), XOR at use (R3 lesson).
// De-risk: R7 passed bit-identical with fp8 x-avg + fp8 W1a -> only tgt-fp8
// noise is new; predicted absmax 0.005-0.008 < 0.0127.

#define NROWS 200000
#define NNODES 100000
#define INF 256
#define KDIM 512
#define HF 512
#define BM 64

typedef __attribute__((ext_vector_type(8))) short short8;
typedef __attribute__((ext_vector_type(4))) float f32x4;
typedef __attribute__((ext_vector_type(2))) float f32x2;

__device__ __align__(16) unsigned char g_h8[NNODES * INF];        // 25.6 MB fp8 e4m3 node table
__device__ __align__(16) unsigned char g_W1p8[HF * KDIM];         // 256 KB fp8 fragment-packed W1

__device__ __forceinline__ unsigned fp8pk4(float a, float b, float c, float d) {
    int w = __builtin_amdgcn_cvt_pk_fp8_f32(a, b, 0, 0);
    w     = __builtin_amdgcn_cvt_pk_fp8_f32(c, d, w, 1);
    return (unsigned)w;
}

// gnn_h fp32 -> fp8 table, 8 elems/thread (12500 blocks x 256).
__global__ void convert_h_kernel(const float* __restrict__ gnn_h) {
    int i = (blockIdx.x * 256 + threadIdx.x) * 8;
    float4 a = *(const float4*)(gnn_h + i);
    float4 b = *(const float4*)(gnn_h + i + 4);
    *(uint2*)(g_h8 + i) = make_uint2(fp8pk4(a.x, a.y, a.z, a.w),
                                     fp8pk4(b.x, b.y, b.z, b.w));
}

// W1 -> fp8 packed in B-fragment order:
// packed[(cg*16+ki)*512 + lane*8 + j] = fp8(W1[cg*16+(lane&15)][ki*32+(lane>>4)*8+j])
// 8 elems (one lane-slot) per thread: 262144/8 = 32768 thr = 128 blocks.
__global__ void pack_w1_kernel(const float* __restrict__ W1) {
    int tid = blockIdx.x * 256 + threadIdx.x;
    int chunk = tid >> 6;           // cg*16 + ki
    int lane  = tid & 63;
    int col = (chunk >> 4) * 16 + (lane & 15);
    int k   = (chunk & 15) * 32 + (lane >> 4) * 8;
    const float4 v0 = *(const float4*)(W1 + col * KDIM + k);
    const float4 v1 = *(const float4*)(W1 + col * KDIM + k + 4);
    *(uint2*)(g_W1p8 + chunk * 512 + lane * 8) =
        make_uint2(fp8pk4(v0.x, v0.y, v0.z, v0.w), fp8pk4(v1.x, v1.y, v1.z, v1.w));
}

__global__ __launch_bounds__(512, 4)
void fused_kernel(const int* __restrict__ tuples,
                  const int* __restrict__ triplets,
                  const float* __restrict__ b1,
                  const float* __restrict__ W2,
                  const float* __restrict__ b2,
                  float* __restrict__ out) {
    __shared__ __align__(16) unsigned char x_lds[BM * KDIM];  // 32 KB fp8, swizzled
    __shared__ int idx_lds[BM * 11];
    __shared__ int tgt_lds[BM];
    __shared__ float red[8][BM];

    const int t = threadIdx.x;
    const int g0 = blockIdx.x * BM;
    const int lane = t & 63;
    const int wc = t >> 6;

    // ---- stage indices ----
    for (int i = t; i < BM * 11; i += 512) idx_lds[i] = tuples[g0 * 11 + i];
    if (t < BM) tgt_lds[t] = triplets[(g0 + t) * 3 + 2];
    __syncthreads();

    // ---- gather: 16 rows/step (32 lanes per row), 4 steps ----
    // avg: 10 x 8B fp8 loads, decode+mean+repack fp8. tgt: straight 8B copy.
    // swizzled LDS: phys = L ^ ((row&15)<<3), L = row*512 + col(byte)
    const int rgrp = t >> 5;
    const int l32 = t & 31;
    for (int step = 0; step < BM / 16; ++step) {
        const int r = step * 16 + rgrp;
        uint2 u[10];
        #pragma unroll
        for (int i = 0; i < 10; ++i) {
            int node = idx_lds[r * 11 + 1 + i];
            node = min(max(node, 0), NNODES - 1);
            u[i] = *(const uint2*)(g_h8 + node * INF + l32 * 8);
        }
        int tg = tgt_lds[r];
        tg = min(max(tg, 0), NNODES - 1);
        const uint2 ut = *(const uint2*)(g_h8 + tg * INF + l32 * 8);

        f32x2 s0 = {0.f, 0.f}, s1 = {0.f, 0.f}, s2 = {0.f, 0.f}, s3 = {0.f, 0.f};
        #pragma unroll
        for (int i = 0; i < 10; ++i) {
            s0 += __builtin_amdgcn_cvt_pk_f32_fp8((int)u[i].x, 0);
            s1 += __builtin_amdgcn_cvt_pk_f32_fp8((int)u[i].x, 1);
            s2 += __builtin_amdgcn_cvt_pk_f32_fp8((int)u[i].y, 0);
            s3 += __builtin_amdgcn_cvt_pk_f32_fp8((int)u[i].y, 1);
        }
        uint2 avg;
        avg.x = fp8pk4(s0.x * 0.1f, s0.y * 0.1f, s1.x * 0.1f, s1.y * 0.1f);
        avg.y = fp8pk4(s2.x * 0.1f, s2.y * 0.1f, s3.x * 0.1f, s3.y * 0.1f);

        const int x = (r & 15) << 3;
        *(uint2*)((char*)x_lds + ((r * 512 + l32 * 8) ^ x)) = avg;
        *(uint2*)((char*)x_lds + ((r * 512 + 256 + l32 * 8) ^ x)) = ut;
    }
    __syncthreads();

    // ---- MFMA: wave wc owns h-cols [wc*64, wc*64+64), acc[4][4], fp8 K-loop ----
    const int arow = lane & 15;
    const int kgrp = lane >> 4;

    f32x4 acc[4][4];
    #pragma unroll
    for (int rt = 0; rt < 4; ++rt)
        #pragma unroll
        for (int ct = 0; ct < 4; ++ct)
            acc[rt][ct] = (f32x4){0.f, 0.f, 0.f, 0.f};

    const int xsw = arow << 3;   // (row&15)<<3, row&15 == arow for rt*16+arow
    for (int ki = 0; ki < 16; ++ki) {
        long a8[4];
        #pragma unroll
        for (int rt = 0; rt < 4; ++rt) {
            const int loff = (rt * 16 + arow) * 512 + ki * 32 + kgrp * 8;
            a8[rt] = *(const long*)((const char*)x_lds + (loff ^ xsw));
        }
        #pragma unroll
        for (int ct = 0; ct < 4; ++ct) {
            const long b8 = *(const long*)(g_W1p8 + ((wc * 4 + ct) * 16 + ki) * 512 + lane * 8);
            #pragma unroll
            for (int rt = 0; rt < 4; ++rt)
                acc[rt][ct] = __builtin_amdgcn_mfma_f32_16x16x32_fp8_fp8(a8[rt], b8, acc[rt][ct], 0, 0, 0);
        }
    }

    // ---- epilogue: relu + dot(W2) + reduce + sigmoid ----
    float b1r[4], w2r[4];
    #pragma unroll
    for (int ct = 0; ct < 4; ++ct) {
        b1r[ct] = b1[wc * 64 + ct * 16 + arow];
        w2r[ct] = W2[wc * 64 + ct * 16 + arow];
    }

    // D mapping: col = wc*64 + ct*16 + (lane&15), row = rt*16 + kgrp*4 + reg
    #pragma unroll
    for (int rt = 0; rt < 4; ++rt) {
        #pragma unroll
        for (int reg = 0; reg < 4; ++reg) {
            float s = 0.f;
            #pragma unroll
            for (int ct = 0; ct < 4; ++ct) {
                float h = acc[rt][ct][reg] + b1r[ct];
                s += fmaxf(h, 0.f) * w2r[ct];
            }
            s += __shfl_xor(s, 1, 64);
            s += __shfl_xor(s, 2, 64);
            s += __shfl_xor(s, 4, 64);
            s += __shfl_xor(s, 8, 64);
            if ((lane & 15) == 0)
                red[wc][rt * 16 + kgrp * 4 + reg] = s;
        }
    }
    __syncthreads();

    if (t < BM) {
        float s = b2[0];
        #pragma unroll
        for (int i = 0; i < 8; ++i) s += red[i][t];
        out[g0 + t] = 1.f / (1.f + expf(-s));
    }
}

extern "C" void kernel_launch(void* const* d_in, const int* in_sizes, int n_in,
                              void* d_out, int out_size, void* d_ws, size_t ws_size,
                              hipStream_t stream) {
    const float* gnn_h    = (const float*)d_in[0];
    const int*   tuples   = (const int*)d_in[1];
    const int*   triplets = (const int*)d_in[2];
    const float* W1       = (const float*)d_in[3];
    const float* b1       = (const float*)d_in[4];
    const float* W2       = (const float*)d_in[5];
    const float* b2       = (const float*)d_in[6];
    float* out = (float*)d_out;

    convert_h_kernel<<<dim3(NNODES * INF / (256 * 8)), dim3(256), 0, stream>>>(gnn_h);
    pack_w1_kernel<<<dim3(HF * KDIM / (256 * 8)), dim3(256), 0, stream>>>(W1);
    fused_kernel<<<dim3(NROWS / BM), dim3(512), 0, stream>>>(
        tuples, triplets, b1, W2, b2, out);
}

// Round 13
// 157.391 us; speedup vs baseline: 2.0368x; 1.4634x over previous
//
#include <hip/hip_runtime.h>
#include <hip/hip_bf16.h>

// TupleAveragePredictor: out = sigmoid( relu( [mean(gnn_h[tuples[:,1:]]), gnn_h[triplets[:,2]]] @ W1^T + b1 ) @ W2^T + b2 )
// R13 = R12 (224us anchor, full-fp8) + B-stream polish: W1 repacked into
// paired-ki 16B/lane chunks (one ulonglong2 load feeds 2 MFMAs; B-load
// instrs halve) + #pragma unroll 2 on the kp loop (compiler double-buffers
// B-loads under MFMA latency). Accumulation order unchanged -> bit-identical
// (absmax tripwire 0.009765625). Warm-replay evidence: kernel is L3-random-
// latency bound; this targets the ~20us exposed L2 B-stream remainder.

#define NROWS 200000
#define NNODES 100000
#define INF 256
#define KDIM 512
#define HF 512
#define BM 64

typedef __attribute__((ext_vector_type(8))) short short8;
typedef __attribute__((ext_vector_type(4))) float f32x4;
typedef __attribute__((ext_vector_type(2))) float f32x2;

__device__ __align__(16) unsigned char g_h8[NNODES * INF];   // 25.6 MB fp8 e4m3 node table
__device__ __align__(16) unsigned char g_W1p8[HF * KDIM];    // 256 KB fp8 paired-ki packed W1

__device__ __forceinline__ unsigned fp8pk4(float a, float b, float c, float d) {
    int w = __builtin_amdgcn_cvt_pk_fp8_f32(a, b, 0, 0);
    w     = __builtin_amdgcn_cvt_pk_fp8_f32(c, d, w, 1);
    return (unsigned)w;
}

// gnn_h fp32 -> fp8 table, 8 elems/thread (12500 blocks x 256).
__global__ void convert_h_kernel(const float* __restrict__ gnn_h) {
    int i = (blockIdx.x * 256 + threadIdx.x) * 8;
    float4 a = *(const float4*)(gnn_h + i);
    float4 b = *(const float4*)(gnn_h + i + 4);
    *(uint2*)(g_h8 + i) = make_uint2(fp8pk4(a.x, a.y, a.z, a.w),
                                     fp8pk4(b.x, b.y, b.z, b.w));
}

// W1 -> fp8 packed, paired-ki chunks of 1024 B:
// pos = (cg*8 + kp)*1024 + lane*16; bytes[0:8] = fragment(cg, ki=2kp, lane),
// bytes[8:16] = fragment(cg, ki=2kp+1, lane), where fragment(cg,ki,lane) =
// fp8(W1[cg*16+(lane&15)][ki*32+(lane>>4)*8 .. +8]).
// 16384 threads (64 blocks x 256), 16 B each.
__global__ void pack_w1_kernel(const float* __restrict__ W1) {
    int tid = blockIdx.x * 256 + threadIdx.x;
    int cg   = tid >> 9;
    int kp   = (tid >> 6) & 7;
    int lane = tid & 63;
    int col = cg * 16 + (lane & 15);
    int ke  = (2 * kp) * 32 + (lane >> 4) * 8;      // ki even
    int ko  = ke + 32;                               // ki odd
    const float4 e0 = *(const float4*)(W1 + col * KDIM + ke);
    const float4 e1 = *(const float4*)(W1 + col * KDIM + ke + 4);
    const float4 o0 = *(const float4*)(W1 + col * KDIM + ko);
    const float4 o1 = *(const float4*)(W1 + col * KDIM + ko + 4);
    uint4 v;
    v.x = fp8pk4(e0.x, e0.y, e0.z, e0.w);
    v.y = fp8pk4(e1.x, e1.y, e1.z, e1.w);
    v.z = fp8pk4(o0.x, o0.y, o0.z, o0.w);
    v.w = fp8pk4(o1.x, o1.y, o1.z, o1.w);
    *(uint4*)(g_W1p8 + (cg * 8 + kp) * 1024 + lane * 16) = v;
}

__global__ __launch_bounds__(512, 4)
void fused_kernel(const int* __restrict__ tuples,
                  const int* __restrict__ triplets,
                  const float* __restrict__ b1,
                  const float* __restrict__ W2,
                  const float* __restrict__ b2,
                  float* __restrict__ out) {
    __shared__ __align__(16) unsigned char x_lds[BM * KDIM];  // 32 KB fp8, swizzled
    __shared__ int idx_lds[BM * 11];
    __shared__ int tgt_lds[BM];
    __shared__ float red[8][BM];

    const int t = threadIdx.x;
    const int g0 = blockIdx.x * BM;
    const int lane = t & 63;
    const int wc = t >> 6;

    // ---- stage indices ----
    for (int i = t; i < BM * 11; i += 512) idx_lds[i] = tuples[g0 * 11 + i];
    if (t < BM) tgt_lds[t] = triplets[(g0 + t) * 3 + 2];
    __syncthreads();

    // ---- gather: 16 rows/step (32 lanes per row), 4 steps (= R12) ----
    // avg: 10 x 8B fp8 loads, decode+mean+repack fp8. tgt: straight 8B copy.
    // swizzled LDS: phys = L ^ ((row&15)<<3), L = row*512 + col(byte)
    const int rgrp = t >> 5;
    const int l32 = t & 31;
    for (int step = 0; step < BM / 16; ++step) {
        const int r = step * 16 + rgrp;
        uint2 u[10];
        #pragma unroll
        for (int i = 0; i < 10; ++i) {
            int node = idx_lds[r * 11 + 1 + i];
            node = min(max(node, 0), NNODES - 1);
            u[i] = *(const uint2*)(g_h8 + node * INF + l32 * 8);
        }
        int tg = tgt_lds[r];
        tg = min(max(tg, 0), NNODES - 1);
        const uint2 ut = *(const uint2*)(g_h8 + tg * INF + l32 * 8);

        f32x2 s0 = {0.f, 0.f}, s1 = {0.f, 0.f}, s2 = {0.f, 0.f}, s3 = {0.f, 0.f};
        #pragma unroll
        for (int i = 0; i < 10; ++i) {
            s0 += __builtin_amdgcn_cvt_pk_f32_fp8((int)u[i].x, 0);
            s1 += __builtin_amdgcn_cvt_pk_f32_fp8((int)u[i].x, 1);
            s2 += __builtin_amdgcn_cvt_pk_f32_fp8((int)u[i].y, 0);
            s3 += __builtin_amdgcn_cvt_pk_f32_fp8((int)u[i].y, 1);
        }
        uint2 avg;
        avg.x = fp8pk4(s0.x * 0.1f, s0.y * 0.1f, s1.x * 0.1f, s1.y * 0.1f);
        avg.y = fp8pk4(s2.x * 0.1f, s2.y * 0.1f, s3.x * 0.1f, s3.y * 0.1f);

        const int x = (r & 15) << 3;
        *(uint2*)((char*)x_lds + ((r * 512 + l32 * 8) ^ x)) = avg;
        *(uint2*)((char*)x_lds + ((r * 512 + 256 + l32 * 8) ^ x)) = ut;
    }
    __syncthreads();

    // ---- MFMA: wave wc owns h-cols [wc*64, wc*64+64), acc[4][4], fp8 ----
    const int arow = lane & 15;
    const int kgrp = lane >> 4;

    f32x4 acc[4][4];
    #pragma unroll
    for (int rt = 0; rt < 4; ++rt)
        #pragma unroll
        for (int ct = 0; ct < 4; ++ct)
            acc[rt][ct] = (f32x4){0.f, 0.f, 0.f, 0.f};

    const int xsw = arow << 3;   // (row&15)<<3, row&15 == arow for rt*16+arow
    #pragma unroll 2
    for (int kp = 0; kp < 8; ++kp) {
        long ae[4], ao[4];       // A frags for ki=2kp, 2kp+1
        #pragma unroll
        for (int rt = 0; rt < 4; ++rt) {
            const int le = (rt * 16 + arow) * 512 + (2 * kp) * 32 + kgrp * 8;
            ae[rt] = *(const long*)((const char*)x_lds + (le ^ xsw));
            ao[rt] = *(const long*)((const char*)x_lds + ((le + 32) ^ xsw));
        }
        #pragma unroll
        for (int ct = 0; ct < 4; ++ct) {
            const ulonglong2 bq = *(const ulonglong2*)(
                g_W1p8 + ((wc * 4 + ct) * 8 + kp) * 1024 + lane * 16);
            const long be = (long)bq.x, bo = (long)bq.y;
            #pragma unroll
            for (int rt = 0; rt < 4; ++rt) {
                acc[rt][ct] = __builtin_amdgcn_mfma_f32_16x16x32_fp8_fp8(ae[rt], be, acc[rt][ct], 0, 0, 0);
                acc[rt][ct] = __builtin_amdgcn_mfma_f32_16x16x32_fp8_fp8(ao[rt], bo, acc[rt][ct], 0, 0, 0);
            }
        }
    }

    // ---- epilogue: relu + dot(W2) + reduce + sigmoid ----
    float b1r[4], w2r[4];
    #pragma unroll
    for (int ct = 0; ct < 4; ++ct) {
        b1r[ct] = b1[wc * 64 + ct * 16 + arow];
        w2r[ct] = W2[wc * 64 + ct * 16 + arow];
    }

    // D mapping: col = wc*64 + ct*16 + (lane&15), row = rt*16 + kgrp*4 + reg
    #pragma unroll
    for (int rt = 0; rt < 4; ++rt) {
        #pragma unroll
        for (int reg = 0; reg < 4; ++reg) {
            float s = 0.f;
            #pragma unroll
            for (int ct = 0; ct < 4; ++ct) {
                float h = acc[rt][ct][reg] + b1r[ct];
                s += fmaxf(h, 0.f) * w2r[ct];
            }
            s += __shfl_xor(s, 1, 64);
            s += __shfl_xor(s, 2, 64);
            s += __shfl_xor(s, 4, 64);
            s += __shfl_xor(s, 8, 64);
            if ((lane & 15) == 0)
                red[wc][rt * 16 + kgrp * 4 + reg] = s;
        }
    }
    __syncthreads();

    if (t < BM) {
        float s = b2[0];
        #pragma unroll
        for (int i = 0; i < 8; ++i) s += red[i][t];
        out[g0 + t] = 1.f / (1.f + expf(-s));
    }
}

extern "C" void kernel_launch(void* const* d_in, const int* in_sizes, int n_in,
                              void* d_out, int out_size, void* d_ws, size_t ws_size,
                              hipStream_t stream) {
    const float* gnn_h    = (const float*)d_in[0];
    const int*   tuples   = (const int*)d_in[1];
    const int*   triplets = (const int*)d_in[2];
    const float* W1       = (const float*)d_in[3];
    const float* b1       = (const float*)d_in[4];
    const float* W2       = (const float*)d_in[5];
    const float* b2       = (const float*)d_in[6];
    float* out = (float*)d_out;

    convert_h_kernel<<<dim3(NNODES * INF / (256 * 8)), dim3(256), 0, stream>>>(gnn_h);
    pack_w1_kernel<<<dim3(64), dim3(256), 0, stream>>>(W1);
    fused_kernel<<<dim3(NROWS / BM), dim3(512), 0, stream>>>(
        tuples, triplets, b1, W2, b2, out);
}